// Round 1
// baseline (669.228 us; speedup 1.0000x reference)
//
#include <hip/hip_runtime.h>
#include <stdint.h>

#define D 128
#define E_EDGES 600000
#define E2 1200000
#define N_USER_C 100000
#define N_ITEM_C 50000
#define NSEG_TOT 150000
#define NCPAD 150528          // 147 * 1024 (scan padding)
#define NEG_SLOPE 0.01f
#define LN_EPS 1e-5f

#define LDPAD 136             // Wt row pitch (halves): 16B-aligned rows
#define GRID_BLOCKS 1024      // blocks per relation
#define TOTAL_BLOCKS (GRID_BLOCKS * 2)
#define GRID_WAVES (GRID_BLOCKS * 4)

typedef __attribute__((ext_vector_type(8))) _Float16 f16x8;
typedef __attribute__((ext_vector_type(2))) _Float16 f16x2;
typedef __attribute__((ext_vector_type(4))) float f32x4;
typedef __attribute__((ext_vector_type(2))) float f32x2;
typedef __attribute__((ext_vector_type(4))) uint32_t u32x4;

// ---------------- joint counting sort (both relations) ----------------
// counters: [0,50000) = item dst of rel u->i ; [50000,150000) = user dst of rel i->u
// joint exclusive scan => rel A occupies sorted[0,600000), rel B [600000,1200000)

__global__ void hist2_k(const int* __restrict__ edst_ui, const int* __restrict__ edst_iu,
                        int* __restrict__ counts) {
    int e = blockIdx.x * 256 + threadIdx.x;
    if (e < E_EDGES) atomicAdd(&counts[edst_ui[e]], 1);
    else if (e < 2 * E_EDGES) atomicAdd(&counts[N_ITEM_C + edst_iu[e - E_EDGES]], 1);
}

__global__ void scan_block_k(const int* __restrict__ counts, int* __restrict__ offsets,
                             int* __restrict__ partial, int n) {
    __shared__ int sm[1024];
    const int t = threadIdx.x;
    const int i = blockIdx.x * 1024 + t;
    int v = (i < n) ? counts[i] : 0;
    sm[t] = v;
    __syncthreads();
    for (int off = 1; off < 1024; off <<= 1) {
        int x = (t >= off) ? sm[t - off] : 0;
        __syncthreads();
        sm[t] += x;
        __syncthreads();
    }
    if (i < n) offsets[i] = sm[t] - v;          // exclusive within block
    if (t == 1023) partial[blockIdx.x] = sm[t]; // block total
}

__global__ void scan_part_k(int* __restrict__ partial, int nb) {
    __shared__ int sm[256];
    const int t = threadIdx.x;
    int v = (t < nb) ? partial[t] : 0;
    sm[t] = v;
    __syncthreads();
    for (int off = 1; off < 256; off <<= 1) {
        int x = (t >= off) ? sm[t - off] : 0;
        __syncthreads();
        sm[t] += x;
        __syncthreads();
    }
    if (t < nb) partial[t] = sm[t] - v;
}

__global__ void scan_add_k(int* __restrict__ offsets, const int* __restrict__ partial,
                           int* __restrict__ counts, int n) {
    const int i = blockIdx.x * 1024 + threadIdx.x;
    if (i < n) {
        offsets[i] += partial[blockIdx.x];
        counts[i] = 0;
    }
}

__global__ void scatter2_k(const int* __restrict__ esrc_ui, const int* __restrict__ edst_ui,
                           const int* __restrict__ esrc_iu, const int* __restrict__ edst_iu,
                           const int* __restrict__ offsets, int* __restrict__ counts,
                           int* __restrict__ sorted) {
    int e = blockIdx.x * 256 + threadIdx.x;
    int s, c;
    if (e < E_EDGES)          { s = esrc_ui[e];            c = edst_ui[e]; }
    else if (e < 2 * E_EDGES) { s = esrc_iu[e - E_EDGES];  c = N_ITEM_C + edst_iu[e - E_EDGES]; }
    else return;
    int pos = offsets[c] + atomicAdd(&counts[c], 1);
    sorted[pos] = s;
}

// ---------------- fused segment-reduced NGCF conv + LayerNorm/ReLU ----------------
// Both relations in one dispatch (rel = blockIdx&1). One wave per dst node.
// fp16 fragments: v_cvt_pkrtz pack + v_pk_mul_f16 product, mfma_f32_16x16x32_f16.
// Padded edge-rows read a zero row (pointer select) so A-row==0 exactly; bias is
// pre-loaded into the accumulator, so each padded row contributes leaky(bias),
// removed in closed form per node. No per-row masking in the hot loop.
//
// launch_bounds(256,2): allocation cap 256 unified regs/wave (a (256,4) cap
// caused scratch spills in an earlier session); actual usage should be ~110-128.
__global__ __launch_bounds__(256, 2) void ngcf_seg2(
    const float* __restrict__ xu, const float* __restrict__ xi,
    const float* __restrict__ W_ui, const float* __restrict__ b_ui,
    const float* __restrict__ W_iu, const float* __restrict__ b_iu,
    const float* __restrict__ lnw_u, const float* __restrict__ lnb_u,
    const float* __restrict__ lnw_i, const float* __restrict__ lnb_i,
    const int* __restrict__ offsets, const int* __restrict__ sorted,
    const float* __restrict__ zrow,
    float* __restrict__ out_user, float* __restrict__ out_item)
{
    __shared__ _Float16 Wt[128 * LDPAD];   // Wt[n][k] = W[k][n]

    const int rel = blockIdx.x & 1;        // 0: u->i (dst items), 1: i->u (dst users)
    const int bid = blockIdx.x >> 1;       // 0..GRID_BLOCKS-1
    const float* __restrict__ xsrc = rel ? xi : xu;
    const float* __restrict__ xdst = rel ? xu : xi;
    const float* __restrict__ Wp   = rel ? W_iu : W_ui;
    const float* __restrict__ bp   = rel ? b_iu : b_ui;
    const float* __restrict__ lnw  = rel ? lnw_u : lnw_i;
    const float* __restrict__ lnb  = rel ? lnb_u : lnb_i;
    float* __restrict__ outp       = rel ? out_user : out_item;
    const int n_dst = rel ? N_USER_C : N_ITEM_C;
    const int obase = rel ? N_ITEM_C : 0;

    const int t = threadIdx.x;
    for (int i = t; i < 128 * 128; i += 256) {
        int k = i >> 7, n = i & 127;
        Wt[n * LDPAD + k] = (_Float16)Wp[i];
    }
    __syncthreads();   // only barrier; Wt read-only afterwards

    const int wv   = t >> 6;
    const int l    = t & 63;
    const int lo16 = l & 15;
    const int quad = l >> 4;

    float bn[8];
    #pragma unroll
    for (int n = 0; n < 8; n++) bn[n] = bp[n * 16 + lo16];

    for (int d = bid * 4 + wv; d < n_dst; d += GRID_WAVES) {
        const int start = offsets[obase + d];
        const int end   = offsets[obase + d + 1];   // obase+d+1 <= 150000 < NCPAD, always valid
        const int len   = end - start;

        // dst row k-slices for this lane, converted to fp16 once per node
        const float4* pd = (const float4*)(xdst + ((size_t)d << 7));
        f16x8 dr[4];
        #pragma unroll
        for (int kt = 0; kt < 4; kt++) {
            float4 c0 = pd[kt * 8 + quad * 2 + 0];
            float4 c1 = pd[kt * 8 + quad * 2 + 1];
            u32x4 u;
            u[0] = __builtin_bit_cast(uint32_t, __builtin_amdgcn_cvt_pkrtz(c0.x, c0.y));
            u[1] = __builtin_bit_cast(uint32_t, __builtin_amdgcn_cvt_pkrtz(c0.z, c0.w));
            u[2] = __builtin_bit_cast(uint32_t, __builtin_amdgcn_cvt_pkrtz(c1.x, c1.y));
            u[3] = __builtin_bit_cast(uint32_t, __builtin_amdgcn_cvt_pkrtz(c1.z, c1.w));
            dr[kt] = __builtin_bit_cast(f16x8, u);
        }

        f32x2 nacc2[8];
        #pragma unroll
        for (int n = 0; n < 8; n++) nacc2[n] = (f32x2){0.f, 0.f};

        for (int c0i = 0; c0i < len; c0i += 16) {
            const int eidx = c0i + lo16;
            const bool okg = eidx < len;
            // sorted is padded by 16 ints; value unused when !okg (pointer overridden)
            const int si = sorted[start + eidx];
            const float4* ps = (const float4*)(okg ? (xsrc + ((size_t)si << 7)) : zrow);

            f32x4 acc[8];
            #pragma unroll
            for (int n = 0; n < 8; n++) acc[n] = (f32x4){bn[n], bn[n], bn[n], bn[n]};

            #pragma unroll
            for (int kt = 0; kt < 4; kt++) {
                float4 a0 = ps[kt * 8 + quad * 2 + 0];
                float4 a1 = ps[kt * 8 + quad * 2 + 1];
                u32x4 u;
                u[0] = __builtin_bit_cast(uint32_t, __builtin_amdgcn_cvt_pkrtz(a0.x, a0.y));
                u[1] = __builtin_bit_cast(uint32_t, __builtin_amdgcn_cvt_pkrtz(a0.z, a0.w));
                u[2] = __builtin_bit_cast(uint32_t, __builtin_amdgcn_cvt_pkrtz(a1.x, a1.y));
                u[3] = __builtin_bit_cast(uint32_t, __builtin_amdgcn_cvt_pkrtz(a1.z, a1.w));
                f16x8 af = __builtin_bit_cast(f16x8, u) * dr[kt];   // v_pk_mul_f16 x4
                #pragma unroll
                for (int n = 0; n < 8; n++) {
                    f16x8 bf = *(const f16x8*)&Wt[(n * 16 + lo16) * LDPAD + kt * 32 + quad * 8];
                    acc[n] = __builtin_amdgcn_mfma_f32_16x16x32_f16(af, bf, acc[n], 0, 0, 0);
                }
            }

            // LeakyReLU = max(x, slope*x) (slope in (0,1)), accumulate all 16 rows
            #pragma unroll
            for (int n = 0; n < 8; n++) {
                f32x2 v01 = (f32x2){acc[n][0], acc[n][1]};
                f32x2 v23 = (f32x2){acc[n][2], acc[n][3]};
                v01 = __builtin_elementwise_max(v01, v01 * NEG_SLOPE);
                v23 = __builtin_elementwise_max(v23, v23 * NEG_SLOPE);
                nacc2[n] += v01 + v23;
            }
        }

        // reduce row-pairs, then across the 4 quads; remove padded-row bias term
        const int nch = (len + 15) >> 4;
        const float inv = (float)(nch * 16 - len);
        float nacc[8];
        #pragma unroll
        for (int n = 0; n < 8; n++) {
            float s = nacc2[n].x + nacc2[n].y;
            s += __shfl_xor(s, 16);
            s += __shfl_xor(s, 32);
            const float lb = fmaxf(bn[n], NEG_SLOPE * bn[n]);   // leaky(bias)
            nacc[n] = s - inv * lb;
        }

        // fused LayerNorm(node) + ReLU. Lane (lo16,*) holds cols {n*16+lo16};
        // xor over bits 0..3 sums the 16 lo16 groups -> all 128 cols.
        float s1 = 0.f, s2 = 0.f;
        #pragma unroll
        for (int n = 0; n < 8; n++) { s1 += nacc[n]; s2 += nacc[n] * nacc[n]; }
        #pragma unroll
        for (int off = 1; off <= 8; off <<= 1) {
            s1 += __shfl_xor(s1, off);
            s2 += __shfl_xor(s2, off);
        }
        const float mu  = s1 * (1.0f / 128.0f);
        const float var = s2 * (1.0f / 128.0f) - mu * mu;
        const float rs  = rsqrtf(var + LN_EPS);

        // each lane stores 2 cols: n in {2*quad, 2*quad+1}
        const int n0 = 2 * quad, n1 = n0 + 1;
        const int col0 = n0 * 16 + lo16, col1 = n1 * 16 + lo16;
        float o0 = (nacc[n0] - mu) * rs * lnw[col0] + lnb[col0];
        float o1 = (nacc[n1] - mu) * rs * lnw[col1] + lnb[col1];
        float* rp = outp + ((size_t)d << 7);
        rp[col0] = fmaxf(o0, 0.f);
        rp[col1] = fmaxf(o1, 0.f);
    }
}

// ---------------- launch ----------------

extern "C" void kernel_launch(void* const* d_in, const int* in_sizes, int n_in,
                              void* d_out, int out_size, void* d_ws, size_t ws_size,
                              hipStream_t stream) {
    const float* x_user    = (const float*)d_in[0];
    const float* x_item    = (const float*)d_in[1];
    const float* W_ui      = (const float*)d_in[2];
    const float* b_ui      = (const float*)d_in[3];
    const float* W_iu      = (const float*)d_in[4];
    const float* b_iu      = (const float*)d_in[5];
    const float* ln_w_user = (const float*)d_in[6];
    const float* ln_b_user = (const float*)d_in[7];
    const float* ln_w_item = (const float*)d_in[8];
    const float* ln_b_item = (const float*)d_in[9];
    const int* esrc_ui = (const int*)d_in[10];
    const int* edst_ui = (const int*)d_in[11];
    const int* esrc_iu = (const int*)d_in[12];
    const int* edst_iu = (const int*)d_in[13];

    float* out = (float*)d_out;
    float* out_user = out;                          // N_USER x D
    float* out_item = out + (size_t)N_USER_C * D;   // N_ITEM x D

    // ws layout (ints): counts[NCPAD] | offsets[NCPAD] | partial[256] |
    //                   sorted[E2+16] | zrow[128 floats]   (~6.0 MB total)
    int* counts  = (int*)d_ws;
    int* offsets = counts + NCPAD;
    int* partial = offsets + NCPAD;
    int* sorted  = partial + 256;
    float* zrow  = (float*)(sorted + E2 + 16);

    const int nb = NCPAD / 1024;   // 147
    hipMemsetAsync(counts, 0, (size_t)NCPAD * sizeof(int), stream);
    hipMemsetAsync(zrow, 0, 128 * sizeof(float), stream);

    hist2_k<<<dim3((2 * E_EDGES + 255) / 256), dim3(256), 0, stream>>>(edst_ui, edst_iu, counts);
    scan_block_k<<<dim3(nb), dim3(1024), 0, stream>>>(counts, offsets, partial, NCPAD);
    scan_part_k<<<dim3(1), dim3(256), 0, stream>>>(partial, nb);
    scan_add_k<<<dim3(nb), dim3(1024), 0, stream>>>(offsets, partial, counts, NCPAD);
    scatter2_k<<<dim3((2 * E_EDGES + 255) / 256), dim3(256), 0, stream>>>(
        esrc_ui, edst_ui, esrc_iu, edst_iu, offsets, counts, sorted);

    ngcf_seg2<<<dim3(TOTAL_BLOCKS), dim3(256), 0, stream>>>(
        x_user, x_item, W_ui, b_ui, W_iu, b_iu,
        ln_w_user, ln_b_user, ln_w_item, ln_b_item,
        offsets, sorted, zrow, out_user, out_item);
}